// Round 7
// baseline (2023.974 us; speedup 1.0000x reference)
//
#include <hip/hip_runtime.h>

typedef short short8 __attribute__((ext_vector_type(8)));
typedef __bf16 bf16x8 __attribute__((ext_vector_type(8)));
typedef float f32x4 __attribute__((ext_vector_type(4)));

#define FEAT 128
#define FPL 2048

__device__ __forceinline__ float b2f(unsigned int u) {
  union { unsigned int u; float f; } c; c.u = u << 16; return c.f;
}
__device__ __forceinline__ unsigned short f2b(float f) {
  union { float f; unsigned int u; } c; c.f = f;
  unsigned int r = c.u + 0x7fffu + ((c.u >> 16) & 1u);
  return (unsigned short)(r >> 16);
}
__device__ __forceinline__ f32x4 mfma16(short8 a, short8 b, f32x4 c) {
  return __builtin_amdgcn_mfma_f32_16x16x32_bf16(
      __builtin_bit_cast(bf16x8, a), __builtin_bit_cast(bf16x8, b), c, 0, 0, 0);
}

// ---- conversion kernels ----
__global__ void cvt_kernel(const float* __restrict__ in, unsigned short* __restrict__ out, int n2) {
  int i = blockIdx.x * 256 + threadIdx.x;
  if (i < n2) {
    float2 v = ((const float2*)in)[i];
    unsigned int lo = f2b(v.x), hi = f2b(v.y);
    ((unsigned int*)out)[i] = lo | (hi << 16);
  }
}

// W[K][N] (row-major) -> WT[N][K] bf16
__global__ void cvtT_kernel(const float* __restrict__ W, unsigned short* __restrict__ WT, int K, int N) {
  int i = blockIdx.x * 256 + threadIdx.x;
  if (i < K * N) {
    int k = i / N, c = i - k * N;
    WT[(size_t)c * K + k] = f2b(W[i]);
  }
}

// ---- CSR build ----
__global__ void count_kernel(const int* __restrict__ dst, int* __restrict__ cnt, int n) {
  int i = blockIdx.x * 256 + threadIdx.x;
  if (i < n) atomicAdd(&cnt[dst[i]], 1);
}

__global__ __launch_bounds__(1024) void scan_kernel(const int* __restrict__ cnt, int* __restrict__ rp, int n) {
  __shared__ int sd[1024];
  __shared__ int carry;
  if (threadIdx.x == 0) carry = 0;
  __syncthreads();
  for (int base = 0; base < n; base += 1024) {
    int i = base + (int)threadIdx.x;
    int v = (i < n) ? cnt[i] : 0;
    sd[threadIdx.x] = v;
    __syncthreads();
    int sum = v;
    for (int off = 1; off < 1024; off <<= 1) {
      int t = (threadIdx.x >= (unsigned)off) ? sd[threadIdx.x - off] : 0;
      __syncthreads();
      sum += t;
      sd[threadIdx.x] = sum;
      __syncthreads();
    }
    if (i < n) rp[i] = carry + sum - v;  // exclusive
    __syncthreads();
    if (threadIdx.x == 1023) carry += sum;
    __syncthreads();
  }
  if (threadIdx.x == 0) rp[n] = carry;
}

__global__ void copy_kernel(const int* __restrict__ a, int* __restrict__ b, int n) {
  int i = blockIdx.x * 256 + threadIdx.x;
  if (i < n) b[i] = a[i];
}

__global__ void fill_kernel(const int* __restrict__ src, const int* __restrict__ dst,
                            int* __restrict__ cursor, int* __restrict__ col, int n) {
  int i = blockIdx.x * 256 + threadIdx.x;
  if (i < n) {
    int p = atomicAdd(&cursor[dst[i]], 1);
    col[p] = src[i];
  }
}

// ---- neighbor gather: agg[i] = x[i] + sum_{j in N(i)} x[j], bf16 in/out, fp32 accum ----
__global__ __launch_bounds__(256) void gather_kernel(const unsigned short* __restrict__ x,
    const int* __restrict__ rp, const int* __restrict__ col,
    unsigned short* __restrict__ agg, int n) {
  int wid = (blockIdx.x * 256 + threadIdx.x) >> 6;
  int lane = threadIdx.x & 63;
  if (wid >= n) return;
  const unsigned int* xw = (const unsigned int*)x;
  unsigned int s = xw[(size_t)wid * 64 + lane];
  float ax = b2f(s & 0xffffu), ay = b2f(s >> 16);
  int beg = rp[wid], end = rp[wid + 1];
  int j = beg;
  for (; j + 4 <= end; j += 4) {
    int c0 = col[j], c1 = col[j + 1], c2 = col[j + 2], c3 = col[j + 3];
    unsigned int v0 = xw[(size_t)c0 * 64 + lane];
    unsigned int v1 = xw[(size_t)c1 * 64 + lane];
    unsigned int v2 = xw[(size_t)c2 * 64 + lane];
    unsigned int v3 = xw[(size_t)c3 * 64 + lane];
    ax += b2f(v0 & 0xffffu) + b2f(v1 & 0xffffu) + b2f(v2 & 0xffffu) + b2f(v3 & 0xffffu);
    ay += b2f(v0 >> 16) + b2f(v1 >> 16) + b2f(v2 >> 16) + b2f(v3 >> 16);
  }
  for (; j < end; ++j) {
    unsigned int v = xw[(size_t)col[j] * 64 + lane];
    ax += b2f(v & 0xffffu);
    ay += b2f(v >> 16);
  }
  ((unsigned int*)agg)[(size_t)wid * 64 + lane] = (unsigned int)f2b(ax) | ((unsigned int)f2b(ay) << 16);
}

// ---- GEMM1: H = relu(A @ W1 + b1), [n,128]x[128,128], bf16 in/out ----
__global__ __launch_bounds__(256) void gemm1_kernel(
    const unsigned short* __restrict__ A, const unsigned short* __restrict__ W1T,
    const float* __restrict__ b1, unsigned short* __restrict__ H, int n) {
  const int wave = threadIdx.x >> 6;
  const int lane = threadIdx.x & 63;
  const int lr = lane & 15, lg = lane >> 4;
  const int rowBase = blockIdx.x * 64 + wave * 16;
  short8 a[4];
#pragma unroll
  for (int kt = 0; kt < 4; ++kt)
    a[kt] = *(const short8*)(A + (size_t)(rowBase + lr) * FEAT + kt * 32 + lg * 8);
  f32x4 acc[8];
#pragma unroll
  for (int ct = 0; ct < 8; ++ct) {
    const unsigned short* bp = W1T + (size_t)(ct * 16 + lr) * FEAT + lg * 8;
    f32x4 c = {0.f, 0.f, 0.f, 0.f};
    c = mfma16(a[0], *(const short8*)(bp), c);
    c = mfma16(a[1], *(const short8*)(bp + 32), c);
    c = mfma16(a[2], *(const short8*)(bp + 64), c);
    c = mfma16(a[3], *(const short8*)(bp + 96), c);
    acc[ct] = c;
  }
#pragma unroll
  for (int ct = 0; ct < 8; ++ct) {
    const int c = ct * 16 + lr;
    const float bias = b1[c];
#pragma unroll
    for (int j = 0; j < 4; ++j) {
      const int row = rowBase + lg * 4 + j;
      if (row < n) {
        float v = acc[ct][j] + bias;
        H[(size_t)row * FEAT + c] = f2b(v > 0.f ? v : 0.f);
      }
    }
  }
}

// ---- statT: partial per-row softmax stats over a 512-col slice ----
// grid = nRowBlk x 4 col-slices; block = 128 rows x 512 cols; wave = 16 rows.
// 4-deep software-pipelined B prefetch (b[4][4], statically indexed via
// unroll-4): round-6 profile showed the allocator crammed this kernel into 32
// VGPRs -> zero in-flight loads -> every W2T L2 latency exposed (217 us,
// MfmaUtil 5%). Forcing ~110 live regs buys a 4-iteration load->use distance.
__global__ __launch_bounds__(512) void statT_kernel(
    const unsigned short* __restrict__ H, const unsigned short* __restrict__ W2T,
    const float* __restrict__ b2, float* __restrict__ pm, float* __restrict__ ps,
    int nPad) {
  const int wave = threadIdx.x >> 6;
  const int lane = threadIdx.x & 63;
  const int lr = lane & 15, lg = lane >> 4;
  const int nRowBlk = nPad >> 7;
  const int rowBlk = blockIdx.x % nRowBlk;
  const int colBlk = blockIdx.x / nRowBlk;
  const int rowBase = rowBlk * 128 + wave * 16;
  const int colBase = colBlk * 512;

  const unsigned short* ap = H + (size_t)(rowBase + lr) * FEAT + lg * 8;
  short8 a0 = *(const short8*)(ap);
  short8 a1 = *(const short8*)(ap + 32);
  short8 a2 = *(const short8*)(ap + 64);
  short8 a3 = *(const short8*)(ap + 96);

  const unsigned short* wb = W2T + (size_t)(colBase + lr) * FEAT + lg * 8;
  const float* bb = b2 + colBase + lr;

  short8 b[4][4];
  float bias[4];
#pragma unroll
  for (int p = 0; p < 4; ++p) {
    const unsigned short* bp = wb + (size_t)p * (16 * FEAT);
    b[p][0] = *(const short8*)(bp);
    b[p][1] = *(const short8*)(bp + 32);
    b[p][2] = *(const short8*)(bp + 64);
    b[p][3] = *(const short8*)(bp + 96);
    bias[p] = bb[p * 16];
  }

  float m[4] = {-1e30f, -1e30f, -1e30f, -1e30f};
  float s[4] = {0.f, 0.f, 0.f, 0.f};
#pragma unroll 4
  for (int ct = 0; ct < 32; ++ct) {
    const int cur = ct & 3;
    f32x4 c0 = {0.f, 0.f, 0.f, 0.f};
    f32x4 c1 = {0.f, 0.f, 0.f, 0.f};
    c0 = mfma16(a0, b[cur][0], c0);
    c1 = mfma16(a1, b[cur][1], c1);
    c0 = mfma16(a2, b[cur][2], c0);
    c1 = mfma16(a3, b[cur][3], c1);
    const float bs = bias[cur];
    // prefetch ct+4 into the buffer just consumed (tail reloads current col)
    const int nc = (ct + 4 < 32) ? ct + 4 : ct;
    const unsigned short* bp = wb + (size_t)nc * (16 * FEAT);
    b[cur][0] = *(const short8*)(bp);
    b[cur][1] = *(const short8*)(bp + 32);
    b[cur][2] = *(const short8*)(bp + 64);
    b[cur][3] = *(const short8*)(bp + 96);
    bias[cur] = bb[nc * 16];

    float e[4];
#pragma unroll
    for (int j = 0; j < 4; ++j) e[j] = c0[j] + c1[j] + bs;
    bool need = (e[0] > m[0] + 8.f) || (e[1] > m[1] + 8.f) ||
                (e[2] > m[2] + 8.f) || (e[3] > m[3] + 8.f);
    if (__any(need)) {
#pragma unroll
      for (int j = 0; j < 4; ++j) {
        float nm = fmaxf(m[j], e[j]);
        s[j] = s[j] * __expf(m[j] - nm) + __expf(e[j] - nm);
        m[j] = nm;
      }
    } else {
#pragma unroll
      for (int j = 0; j < 4; ++j) s[j] += __expf(e[j] - m[j]);
    }
  }
  // merge across the 16 lr lanes (distinct col sub-slices of the same rows)
#pragma unroll
  for (int j = 0; j < 4; ++j) {
#pragma unroll
    for (int d = 1; d < 16; d <<= 1) {
      float om = __shfl_xor(m[j], d, 64);
      float os = __shfl_xor(s[j], d, 64);
      float nm = fmaxf(m[j], om);
      s[j] = s[j] * __expf(m[j] - nm) + os * __expf(om - nm);
      m[j] = nm;
    }
  }
  if (lr == 0) {
#pragma unroll
    for (int j = 0; j < 4; ++j) {
      const int row = rowBase + lg * 4 + j;
      pm[(size_t)colBlk * nPad + row] = m[j];
      ps[(size_t)colBlk * nPad + row] = s[j];
    }
  }
}

// ---- mergeT: T[r] = M + ln(sum_k s_k * exp(m_k - M)) over the 4 col-slices ----
__global__ void mergeT_kernel(const float* __restrict__ pm, const float* __restrict__ ps,
                              float* __restrict__ T, int nPad) {
  int r = blockIdx.x * 256 + threadIdx.x;
  if (r < nPad) {
    float M = pm[r];
#pragma unroll
    for (int k = 1; k < 4; ++k) M = fmaxf(M, pm[(size_t)k * nPad + r]);
    float S = 0.f;
#pragma unroll
    for (int k = 0; k < 4; ++k) S += ps[(size_t)k * nPad + r] * __expf(pm[(size_t)k * nPad + r] - M);
    T[r] = M + __logf(S);
  }
}

// ---- fpacc: recompute logits, fp_partial[c] += sum_r exp(l[r,c] - T[r]) ----
// same split + same 4-deep pipelined prefetch as statT.
__global__ __launch_bounds__(512) void fpacc_kernel(
    const unsigned short* __restrict__ H, const unsigned short* __restrict__ W2T,
    const float* __restrict__ b2, const float* __restrict__ T,
    float* __restrict__ partials, int n, int nPad) {
  __shared__ float fp_w[8][512];
  const int wave = threadIdx.x >> 6;
  const int lane = threadIdx.x & 63;
  const int lr = lane & 15, lg = lane >> 4;
  const int nRowBlk = nPad >> 7;
  const int rowBlk = blockIdx.x % nRowBlk;
  const int colBlk = blockIdx.x / nRowBlk;
  const int rowBase = rowBlk * 128 + wave * 16;
  const int colBase = colBlk * 512;

  const unsigned short* ap = H + (size_t)(rowBase + lr) * FEAT + lg * 8;
  short8 a0 = *(const short8*)(ap);
  short8 a1 = *(const short8*)(ap + 32);
  short8 a2 = *(const short8*)(ap + 64);
  short8 a3 = *(const short8*)(ap + 96);
  float Tj[4];
#pragma unroll
  for (int j = 0; j < 4; ++j) {
    const int row = rowBase + lg * 4 + j;
    Tj[j] = (row < n) ? T[row] : 1e30f;  // pad rows contribute 0
  }

  const unsigned short* wb = W2T + (size_t)(colBase + lr) * FEAT + lg * 8;
  const float* bb = b2 + colBase + lr;

  short8 b[4][4];
  float bias[4];
#pragma unroll
  for (int p = 0; p < 4; ++p) {
    const unsigned short* bp = wb + (size_t)p * (16 * FEAT);
    b[p][0] = *(const short8*)(bp);
    b[p][1] = *(const short8*)(bp + 32);
    b[p][2] = *(const short8*)(bp + 64);
    b[p][3] = *(const short8*)(bp + 96);
    bias[p] = bb[p * 16];
  }

#pragma unroll 4
  for (int ct = 0; ct < 32; ++ct) {
    const int cur = ct & 3;
    f32x4 c0 = {0.f, 0.f, 0.f, 0.f};
    f32x4 c1 = {0.f, 0.f, 0.f, 0.f};
    c0 = mfma16(a0, b[cur][0], c0);
    c1 = mfma16(a1, b[cur][1], c1);
    c0 = mfma16(a2, b[cur][2], c0);
    c1 = mfma16(a3, b[cur][3], c1);
    const float bs = bias[cur];
    const int nc = (ct + 4 < 32) ? ct + 4 : ct;
    const unsigned short* bp = wb + (size_t)nc * (16 * FEAT);
    b[cur][0] = *(const short8*)(bp);
    b[cur][1] = *(const short8*)(bp + 32);
    b[cur][2] = *(const short8*)(bp + 64);
    b[cur][3] = *(const short8*)(bp + 96);
    bias[cur] = bb[nc * 16];

    float p = __expf(c0[0] + c1[0] + bs - Tj[0]) + __expf(c0[1] + c1[1] + bs - Tj[1]) +
              __expf(c0[2] + c1[2] + bs - Tj[2]) + __expf(c0[3] + c1[3] + bs - Tj[3]);
    p += __shfl_xor(p, 16, 64);
    p += __shfl_xor(p, 32, 64);
    if (lg == 0) fp_w[wave][ct * 16 + lr] = p;  // disjoint cols per ct: plain write
  }
  __syncthreads();
  const int i = threadIdx.x;  // 512 threads == 512 cols
  float sum = 0.f;
#pragma unroll
  for (int w = 0; w < 8; ++w) sum += fp_w[w][i];
  partials[(size_t)rowBlk * FPL + colBase + i] += sum;
}

__global__ void reduce_kernel(const float* __restrict__ partials, float* __restrict__ out, int nPart) {
  int c = blockIdx.x * 256 + threadIdx.x;
  if (c < FPL) {
    float s = 0.f;
    for (int p = 0; p < nPart; ++p) s += partials[(size_t)p * FPL + c];
    out[c] = s;
  }
}

extern "C" void kernel_launch(void* const* d_in, const int* in_sizes, int n_in,
                              void* d_out, int out_size, void* d_ws, size_t ws_size,
                              hipStream_t stream) {
  const float* atoms = (const float*)d_in[0];
  const float* W1 = (const float*)d_in[1];
  const float* b1 = (const float*)d_in[2];
  const float* W2 = (const float*)d_in[3];
  const float* b2 = (const float*)d_in[4];
  const int* esrc = (const int*)d_in[5];
  const int* edst = (const int*)d_in[6];
  const int nAtoms = in_sizes[0] / FEAT;
  const int nEdges = in_sizes[5];
  if (nAtoms <= 0) return;

  const int g2Blocks = (nAtoms + 127) / 128;  // 128-row tiles
  const int nPad = g2Blocks * 128;
  const int g1Blocks = nPad / 64;

  size_t off = 0;
  auto alloc = [&](size_t bytes) -> void* {
    void* p = (char*)d_ws + off;
    off += (bytes + 255) & ~(size_t)255;
    return p;
  };
  unsigned short* P = (unsigned short*)alloc((size_t)nPad * FEAT * 2);
  unsigned short* Q = (unsigned short*)alloc((size_t)nPad * FEAT * 2);
  unsigned short* W1T = (unsigned short*)alloc((size_t)FEAT * FEAT * 2);
  unsigned short* W2T = (unsigned short*)alloc((size_t)FEAT * FPL * 2);
  int* counts = (int*)alloc((size_t)nAtoms * 4);
  int* cursor = (int*)alloc((size_t)nAtoms * 4);
  int* rp = (int*)alloc(((size_t)nAtoms + 1) * 4);
  int* col = (int*)alloc((size_t)nEdges * 4);
  float* pm = (float*)alloc((size_t)4 * nPad * 4);
  float* ps = (float*)alloc((size_t)4 * nPad * 4);
  float* Trow = (float*)alloc((size_t)nPad * 4);
  float* partials = (float*)alloc((size_t)g2Blocks * FPL * 4);

  hipMemsetAsync(counts, 0, (size_t)nAtoms * 4, stream);
  hipMemsetAsync(partials, 0, (size_t)g2Blocks * FPL * 4, stream);
  hipMemsetAsync(P + (size_t)nAtoms * FEAT, 0, (size_t)(nPad - nAtoms) * FEAT * 2, stream);
  hipMemsetAsync(Q + (size_t)nAtoms * FEAT, 0, (size_t)(nPad - nAtoms) * FEAT * 2, stream);

  const int n2 = in_sizes[0] / 2;
  cvt_kernel<<<(n2 + 255) / 256, 256, 0, stream>>>(atoms, P, n2);
  cvtT_kernel<<<(FEAT * FEAT + 255) / 256, 256, 0, stream>>>(W1, W1T, FEAT, FEAT);
  cvtT_kernel<<<(FEAT * FPL + 255) / 256, 256, 0, stream>>>(W2, W2T, FEAT, FPL);
  count_kernel<<<(nEdges + 255) / 256, 256, 0, stream>>>(edst, counts, nEdges);
  scan_kernel<<<1, 1024, 0, stream>>>(counts, rp, nAtoms);
  copy_kernel<<<(nAtoms + 255) / 256, 256, 0, stream>>>(rp, cursor, nAtoms);
  fill_kernel<<<(nEdges + 255) / 256, 256, 0, stream>>>(esrc, edst, cursor, col, nEdges);

  unsigned short* x = P;
  unsigned short* y = Q;
  for (int step = 0; step < 3; ++step) {
    gather_kernel<<<(nAtoms + 3) / 4, 256, 0, stream>>>(x, rp, col, y, nAtoms);
    gemm1_kernel<<<g1Blocks, 256, 0, stream>>>(y, W1T, b1, y, nAtoms);
    statT_kernel<<<g2Blocks * 4, 512, 0, stream>>>(y, W2T, b2, pm, ps, nPad);
    mergeT_kernel<<<(nPad + 255) / 256, 256, 0, stream>>>(pm, ps, Trow, nPad);
    fpacc_kernel<<<g2Blocks * 4, 512, 0, stream>>>(y, W2T, b2, Trow, partials, nAtoms, nPad);
    unsigned short* t = x; x = y; y = t;
  }
  reduce_kernel<<<(FPL + 255) / 256, 256, 0, stream>>>(partials, (float*)d_out, g2Blocks);
}

// Round 8
// 899.020 us; speedup vs baseline: 2.2513x; 2.2513x over previous
//
#include <hip/hip_runtime.h>

typedef short short8 __attribute__((ext_vector_type(8)));
typedef __bf16 bf16x8 __attribute__((ext_vector_type(8)));
typedef float f32x4 __attribute__((ext_vector_type(4)));

#define FEAT 128
#define FPL 2048

__device__ __forceinline__ float b2f(unsigned int u) {
  union { unsigned int u; float f; } c; c.u = u << 16; return c.f;
}
__device__ __forceinline__ unsigned short f2b(float f) {
  union { float f; unsigned int u; } c; c.f = f;
  unsigned int r = c.u + 0x7fffu + ((c.u >> 16) & 1u);
  return (unsigned short)(r >> 16);
}
__device__ __forceinline__ f32x4 mfma16(short8 a, short8 b, f32x4 c) {
  return __builtin_amdgcn_mfma_f32_16x16x32_bf16(
      __builtin_bit_cast(bf16x8, a), __builtin_bit_cast(bf16x8, b), c, 0, 0, 0);
}

// ---- conversion kernels ----
__global__ void cvt_kernel(const float* __restrict__ in, unsigned short* __restrict__ out, int n2) {
  int i = blockIdx.x * 256 + threadIdx.x;
  if (i < n2) {
    float2 v = ((const float2*)in)[i];
    unsigned int lo = f2b(v.x), hi = f2b(v.y);
    ((unsigned int*)out)[i] = lo | (hi << 16);
  }
}

// W[K][N] (row-major) -> WT[N][K] bf16
__global__ void cvtT_kernel(const float* __restrict__ W, unsigned short* __restrict__ WT, int K, int N) {
  int i = blockIdx.x * 256 + threadIdx.x;
  if (i < K * N) {
    int k = i / N, c = i - k * N;
    WT[(size_t)c * K + k] = f2b(W[i]);
  }
}

// ---- CSR build ----
__global__ void count_kernel(const int* __restrict__ dst, int* __restrict__ cnt, int n) {
  int i = blockIdx.x * 256 + threadIdx.x;
  if (i < n) atomicAdd(&cnt[dst[i]], 1);
}

__global__ __launch_bounds__(1024) void scan_kernel(const int* __restrict__ cnt, int* __restrict__ rp, int n) {
  __shared__ int sd[1024];
  __shared__ int carry;
  if (threadIdx.x == 0) carry = 0;
  __syncthreads();
  for (int base = 0; base < n; base += 1024) {
    int i = base + (int)threadIdx.x;
    int v = (i < n) ? cnt[i] : 0;
    sd[threadIdx.x] = v;
    __syncthreads();
    int sum = v;
    for (int off = 1; off < 1024; off <<= 1) {
      int t = (threadIdx.x >= (unsigned)off) ? sd[threadIdx.x - off] : 0;
      __syncthreads();
      sum += t;
      sd[threadIdx.x] = sum;
      __syncthreads();
    }
    if (i < n) rp[i] = carry + sum - v;  // exclusive
    __syncthreads();
    if (threadIdx.x == 1023) carry += sum;
    __syncthreads();
  }
  if (threadIdx.x == 0) rp[n] = carry;
}

__global__ void copy_kernel(const int* __restrict__ a, int* __restrict__ b, int n) {
  int i = blockIdx.x * 256 + threadIdx.x;
  if (i < n) b[i] = a[i];
}

__global__ void fill_kernel(const int* __restrict__ src, const int* __restrict__ dst,
                            int* __restrict__ cursor, int* __restrict__ col, int n) {
  int i = blockIdx.x * 256 + threadIdx.x;
  if (i < n) {
    int p = atomicAdd(&cursor[dst[i]], 1);
    col[p] = src[i];
  }
}

// ---- neighbor gather: agg[i] = x[i] + sum_{j in N(i)} x[j], bf16 in/out, fp32 accum ----
__global__ __launch_bounds__(256) void gather_kernel(const unsigned short* __restrict__ x,
    const int* __restrict__ rp, const int* __restrict__ col,
    unsigned short* __restrict__ agg, int n) {
  int wid = (blockIdx.x * 256 + threadIdx.x) >> 6;
  int lane = threadIdx.x & 63;
  if (wid >= n) return;
  const unsigned int* xw = (const unsigned int*)x;
  unsigned int s = xw[(size_t)wid * 64 + lane];
  float ax = b2f(s & 0xffffu), ay = b2f(s >> 16);
  int beg = rp[wid], end = rp[wid + 1];
  int j = beg;
  for (; j + 4 <= end; j += 4) {
    int c0 = col[j], c1 = col[j + 1], c2 = col[j + 2], c3 = col[j + 3];
    unsigned int v0 = xw[(size_t)c0 * 64 + lane];
    unsigned int v1 = xw[(size_t)c1 * 64 + lane];
    unsigned int v2 = xw[(size_t)c2 * 64 + lane];
    unsigned int v3 = xw[(size_t)c3 * 64 + lane];
    ax += b2f(v0 & 0xffffu) + b2f(v1 & 0xffffu) + b2f(v2 & 0xffffu) + b2f(v3 & 0xffffu);
    ay += b2f(v0 >> 16) + b2f(v1 >> 16) + b2f(v2 >> 16) + b2f(v3 >> 16);
  }
  for (; j < end; ++j) {
    unsigned int v = xw[(size_t)col[j] * 64 + lane];
    ax += b2f(v & 0xffffu);
    ay += b2f(v >> 16);
  }
  ((unsigned int*)agg)[(size_t)wid * 64 + lane] = (unsigned int)f2b(ax) | ((unsigned int)f2b(ay) << 16);
}

// ---- GEMM1: H = relu(A @ W1 + b1), [n,128]x[128,128], bf16 in/out ----
__global__ __launch_bounds__(256) void gemm1_kernel(
    const unsigned short* __restrict__ A, const unsigned short* __restrict__ W1T,
    const float* __restrict__ b1, unsigned short* __restrict__ H, int n) {
  const int wave = threadIdx.x >> 6;
  const int lane = threadIdx.x & 63;
  const int lr = lane & 15, lg = lane >> 4;
  const int rowBase = blockIdx.x * 64 + wave * 16;
  short8 a[4];
#pragma unroll
  for (int kt = 0; kt < 4; ++kt)
    a[kt] = *(const short8*)(A + (size_t)(rowBase + lr) * FEAT + kt * 32 + lg * 8);
  f32x4 acc[8];
#pragma unroll
  for (int ct = 0; ct < 8; ++ct) {
    const unsigned short* bp = W1T + (size_t)(ct * 16 + lr) * FEAT + lg * 8;
    f32x4 c = {0.f, 0.f, 0.f, 0.f};
    c = mfma16(a[0], *(const short8*)(bp), c);
    c = mfma16(a[1], *(const short8*)(bp + 32), c);
    c = mfma16(a[2], *(const short8*)(bp + 64), c);
    c = mfma16(a[3], *(const short8*)(bp + 96), c);
    acc[ct] = c;
  }
#pragma unroll
  for (int ct = 0; ct < 8; ++ct) {
    const int c = ct * 16 + lr;
    const float bias = b1[c];
#pragma unroll
    for (int j = 0; j < 4; ++j) {
      const int row = rowBase + lg * 4 + j;
      if (row < n) {
        float v = acc[ct][j] + bias;
        H[(size_t)row * FEAT + c] = f2b(v > 0.f ? v : 0.f);
      }
    }
  }
}

// ================= LDS-staged GEMM2 passes =================
// Block = 256 rows x 256 cols; 8 waves x 32 rows (2 groups of 16); the block's
// whole W2T slice (64 KB) + bias (1 KB) staged into LDS ONCE, fragment-major
// (pair p = ct*4+q, slot = lane) so ds_read_b128 is the contiguous
// conflict-free pattern. Rounds 5-7 proved per-wave global fragment loads are
// latency-bound (MfmaUtil 4%, nothing busy); staging shares one load across
// 8 waves x 16 iterations and LDS->MFMA is compiler-scheduled (fine lgkmcnt).

// ---- statT: partial per-row online-softmax stats over a 256-col slice ----
__global__ __launch_bounds__(512) void statT_kernel(
    const unsigned short* __restrict__ H, const unsigned short* __restrict__ W2T,
    const float* __restrict__ b2, float* __restrict__ pm, float* __restrict__ ps,
    int nPad) {
  __shared__ short8 ldsB[4096];   // 64 KB
  __shared__ float ldsBias[256];
  const int wave = threadIdx.x >> 6;
  const int lane = threadIdx.x & 63;
  const int lr = lane & 15, lg = lane >> 4;
  const int nRowBlk = nPad >> 8;
  const int rowBlk = blockIdx.x % nRowBlk;
  const int colBlk = blockIdx.x / nRowBlk;
  const int rowBase = rowBlk * 256 + wave * 32;
  const int colBase = colBlk * 256;

#pragma unroll
  for (int r = 0; r < 8; ++r) {
    const int p = r * 8 + wave;
    const int ct = p >> 2, q = p & 3;
    ldsB[p * 64 + lane] =
        *(const short8*)(W2T + (size_t)(colBase + ct * 16 + lr) * FEAT + (q * 4 + lg) * 8);
  }
  if (threadIdx.x < 256) ldsBias[threadIdx.x] = b2[colBase + threadIdx.x];

  short8 a[2][4];
#pragma unroll
  for (int g = 0; g < 2; ++g)
#pragma unroll
    for (int kt = 0; kt < 4; ++kt)
      a[g][kt] = *(const short8*)(H + (size_t)(rowBase + g * 16 + lr) * FEAT + kt * 32 + lg * 8);
  __syncthreads();

  float m[2][4], s[2][4];
#pragma unroll
  for (int g = 0; g < 2; ++g)
#pragma unroll
    for (int j = 0; j < 4; ++j) { m[g][j] = -1e30f; s[g][j] = 0.f; }

#pragma unroll 4
  for (int ct = 0; ct < 16; ++ct) {
    short8 q0 = ldsB[(ct * 4 + 0) * 64 + lane];
    short8 q1 = ldsB[(ct * 4 + 1) * 64 + lane];
    short8 q2 = ldsB[(ct * 4 + 2) * 64 + lane];
    short8 q3 = ldsB[(ct * 4 + 3) * 64 + lane];
    f32x4 c0 = {0.f, 0.f, 0.f, 0.f};
    f32x4 c1 = {0.f, 0.f, 0.f, 0.f};
    c0 = mfma16(a[0][0], q0, c0);
    c1 = mfma16(a[1][0], q0, c1);
    c0 = mfma16(a[0][1], q1, c0);
    c1 = mfma16(a[1][1], q1, c1);
    c0 = mfma16(a[0][2], q2, c0);
    c1 = mfma16(a[1][2], q2, c1);
    c0 = mfma16(a[0][3], q3, c0);
    c1 = mfma16(a[1][3], q3, c1);
    const float bs = ldsBias[ct * 16 + lr];
    float e0[4], e1[4];
#pragma unroll
    for (int j = 0; j < 4; ++j) { e0[j] = c0[j] + bs; e1[j] = c1[j] + bs; }
    bool need = false;
#pragma unroll
    for (int j = 0; j < 4; ++j)
      need = need || (e0[j] > m[0][j] + 8.f) || (e1[j] > m[1][j] + 8.f);
    if (__any(need)) {
#pragma unroll
      for (int j = 0; j < 4; ++j) {
        float nm0 = fmaxf(m[0][j], e0[j]);
        s[0][j] = s[0][j] * __expf(m[0][j] - nm0) + __expf(e0[j] - nm0);
        m[0][j] = nm0;
        float nm1 = fmaxf(m[1][j], e1[j]);
        s[1][j] = s[1][j] * __expf(m[1][j] - nm1) + __expf(e1[j] - nm1);
        m[1][j] = nm1;
      }
    } else {
#pragma unroll
      for (int j = 0; j < 4; ++j) {
        s[0][j] += __expf(e0[j] - m[0][j]);
        s[1][j] += __expf(e1[j] - m[1][j]);
      }
    }
  }
  // merge across the 16 lr lanes (distinct col sub-slices of the same rows)
#pragma unroll
  for (int g = 0; g < 2; ++g)
#pragma unroll
    for (int j = 0; j < 4; ++j) {
#pragma unroll
      for (int d = 1; d < 16; d <<= 1) {
        float om = __shfl_xor(m[g][j], d, 64);
        float os = __shfl_xor(s[g][j], d, 64);
        float nm = fmaxf(m[g][j], om);
        s[g][j] = s[g][j] * __expf(m[g][j] - nm) + os * __expf(om - nm);
        m[g][j] = nm;
      }
    }
  if (lr == 0) {
#pragma unroll
    for (int g = 0; g < 2; ++g)
#pragma unroll
      for (int j = 0; j < 4; ++j) {
        const int row = rowBase + g * 16 + lg * 4 + j;
        pm[(size_t)colBlk * nPad + row] = m[g][j];
        ps[(size_t)colBlk * nPad + row] = s[g][j];
      }
  }
}

// ---- mergeT: T[r] = M + ln(sum_k s_k * exp(m_k - M)) over the 8 col-slices ----
__global__ void mergeT_kernel(const float* __restrict__ pm, const float* __restrict__ ps,
                              float* __restrict__ T, int nPad) {
  int r = blockIdx.x * 256 + threadIdx.x;
  if (r < nPad) {
    float M = pm[r];
#pragma unroll
    for (int k = 1; k < 8; ++k) M = fmaxf(M, pm[(size_t)k * nPad + r]);
    float S = 0.f;
#pragma unroll
    for (int k = 0; k < 8; ++k) S += ps[(size_t)k * nPad + r] * __expf(pm[(size_t)k * nPad + r] - M);
    T[r] = M + __logf(S);
  }
}

// ---- fpacc: recompute logits, fp_partial[c] += sum_r exp(l[r,c] - T[r]) ----
__global__ __launch_bounds__(512) void fpacc_kernel(
    const unsigned short* __restrict__ H, const unsigned short* __restrict__ W2T,
    const float* __restrict__ b2, const float* __restrict__ T,
    float* __restrict__ partials, int n, int nPad) {
  __shared__ short8 ldsB[4096];   // 64 KB
  __shared__ float ldsBias[256];
  __shared__ float fp_w[8][256];  // 8 KB
  const int wave = threadIdx.x >> 6;
  const int lane = threadIdx.x & 63;
  const int lr = lane & 15, lg = lane >> 4;
  const int nRowBlk = nPad >> 8;
  const int rowBlk = blockIdx.x % nRowBlk;
  const int colBlk = blockIdx.x / nRowBlk;
  const int rowBase = rowBlk * 256 + wave * 32;
  const int colBase = colBlk * 256;

#pragma unroll
  for (int r = 0; r < 8; ++r) {
    const int p = r * 8 + wave;
    const int ct = p >> 2, q = p & 3;
    ldsB[p * 64 + lane] =
        *(const short8*)(W2T + (size_t)(colBase + ct * 16 + lr) * FEAT + (q * 4 + lg) * 8);
  }
  if (threadIdx.x < 256) ldsBias[threadIdx.x] = b2[colBase + threadIdx.x];

  short8 a[2][4];
#pragma unroll
  for (int g = 0; g < 2; ++g)
#pragma unroll
    for (int kt = 0; kt < 4; ++kt)
      a[g][kt] = *(const short8*)(H + (size_t)(rowBase + g * 16 + lr) * FEAT + kt * 32 + lg * 8);
  float Tj[2][4];
#pragma unroll
  for (int g = 0; g < 2; ++g)
#pragma unroll
    for (int j = 0; j < 4; ++j) {
      const int row = rowBase + g * 16 + lg * 4 + j;
      Tj[g][j] = (row < n) ? T[row] : 1e30f;  // pad rows contribute 0
    }
  __syncthreads();

#pragma unroll 4
  for (int ct = 0; ct < 16; ++ct) {
    short8 q0 = ldsB[(ct * 4 + 0) * 64 + lane];
    short8 q1 = ldsB[(ct * 4 + 1) * 64 + lane];
    short8 q2 = ldsB[(ct * 4 + 2) * 64 + lane];
    short8 q3 = ldsB[(ct * 4 + 3) * 64 + lane];
    f32x4 c0 = {0.f, 0.f, 0.f, 0.f};
    f32x4 c1 = {0.f, 0.f, 0.f, 0.f};
    c0 = mfma16(a[0][0], q0, c0);
    c1 = mfma16(a[1][0], q0, c1);
    c0 = mfma16(a[0][1], q1, c0);
    c1 = mfma16(a[1][1], q1, c1);
    c0 = mfma16(a[0][2], q2, c0);
    c1 = mfma16(a[1][2], q2, c1);
    c0 = mfma16(a[0][3], q3, c0);
    c1 = mfma16(a[1][3], q3, c1);
    const float bs = ldsBias[ct * 16 + lr];
    float p = __expf(c0[0] + bs - Tj[0][0]) + __expf(c0[1] + bs - Tj[0][1]) +
              __expf(c0[2] + bs - Tj[0][2]) + __expf(c0[3] + bs - Tj[0][3]) +
              __expf(c1[0] + bs - Tj[1][0]) + __expf(c1[1] + bs - Tj[1][1]) +
              __expf(c1[2] + bs - Tj[1][2]) + __expf(c1[3] + bs - Tj[1][3]);
    p += __shfl_xor(p, 16, 64);
    p += __shfl_xor(p, 32, 64);
    if (lg == 0) fp_w[wave][ct * 16 + lr] = p;
  }
  __syncthreads();
  if (threadIdx.x < 256) {
    float sum = 0.f;
#pragma unroll
    for (int w = 0; w < 8; ++w) sum += fp_w[w][threadIdx.x];
    partials[(size_t)rowBlk * FPL + colBase + threadIdx.x] += sum;
  }
}

__global__ void reduce_kernel(const float* __restrict__ partials, float* __restrict__ out, int nPart) {
  int c = blockIdx.x * 256 + threadIdx.x;
  if (c < FPL) {
    float s = 0.f;
    for (int p = 0; p < nPart; ++p) s += partials[(size_t)p * FPL + c];
    out[c] = s;
  }
}

extern "C" void kernel_launch(void* const* d_in, const int* in_sizes, int n_in,
                              void* d_out, int out_size, void* d_ws, size_t ws_size,
                              hipStream_t stream) {
  const float* atoms = (const float*)d_in[0];
  const float* W1 = (const float*)d_in[1];
  const float* b1 = (const float*)d_in[2];
  const float* W2 = (const float*)d_in[3];
  const float* b2 = (const float*)d_in[4];
  const int* esrc = (const int*)d_in[5];
  const int* edst = (const int*)d_in[6];
  const int nAtoms = in_sizes[0] / FEAT;
  const int nEdges = in_sizes[5];
  if (nAtoms <= 0) return;

  const int g2Blocks = (nAtoms + 255) / 256;  // 256-row tiles for statT/fpacc
  const int nPad = g2Blocks * 256;
  const int g1Blocks = nPad / 64;

  size_t off = 0;
  auto alloc = [&](size_t bytes) -> void* {
    void* p = (char*)d_ws + off;
    off += (bytes + 255) & ~(size_t)255;
    return p;
  };
  unsigned short* P = (unsigned short*)alloc((size_t)nPad * FEAT * 2);
  unsigned short* Q = (unsigned short*)alloc((size_t)nPad * FEAT * 2);
  unsigned short* W1T = (unsigned short*)alloc((size_t)FEAT * FEAT * 2);
  unsigned short* W2T = (unsigned short*)alloc((size_t)FEAT * FPL * 2);
  int* counts = (int*)alloc((size_t)nAtoms * 4);
  int* cursor = (int*)alloc((size_t)nAtoms * 4);
  int* rp = (int*)alloc(((size_t)nAtoms + 1) * 4);
  int* col = (int*)alloc((size_t)nEdges * 4);
  float* pm = (float*)alloc((size_t)8 * nPad * 4);
  float* ps = (float*)alloc((size_t)8 * nPad * 4);
  float* Trow = (float*)alloc((size_t)nPad * 4);
  float* partials = (float*)alloc((size_t)g2Blocks * FPL * 4);

  hipMemsetAsync(counts, 0, (size_t)nAtoms * 4, stream);
  hipMemsetAsync(partials, 0, (size_t)g2Blocks * FPL * 4, stream);
  hipMemsetAsync(P + (size_t)nAtoms * FEAT, 0, (size_t)(nPad - nAtoms) * FEAT * 2, stream);
  hipMemsetAsync(Q + (size_t)nAtoms * FEAT, 0, (size_t)(nPad - nAtoms) * FEAT * 2, stream);

  const int n2 = in_sizes[0] / 2;
  cvt_kernel<<<(n2 + 255) / 256, 256, 0, stream>>>(atoms, P, n2);
  cvtT_kernel<<<(FEAT * FEAT + 255) / 256, 256, 0, stream>>>(W1, W1T, FEAT, FEAT);
  cvtT_kernel<<<(FEAT * FPL + 255) / 256, 256, 0, stream>>>(W2, W2T, FEAT, FPL);
  count_kernel<<<(nEdges + 255) / 256, 256, 0, stream>>>(edst, counts, nEdges);
  scan_kernel<<<1, 1024, 0, stream>>>(counts, rp, nAtoms);
  copy_kernel<<<(nAtoms + 255) / 256, 256, 0, stream>>>(rp, cursor, nAtoms);
  fill_kernel<<<(nEdges + 255) / 256, 256, 0, stream>>>(esrc, edst, cursor, col, nEdges);

  unsigned short* x = P;
  unsigned short* y = Q;
  for (int step = 0; step < 3; ++step) {
    gather_kernel<<<(nAtoms + 3) / 4, 256, 0, stream>>>(x, rp, col, y, nAtoms);
    gemm1_kernel<<<g1Blocks, 256, 0, stream>>>(y, W1T, b1, y, nAtoms);
    statT_kernel<<<g2Blocks * 8, 512, 0, stream>>>(y, W2T, b2, pm, ps, nPad);
    mergeT_kernel<<<(nPad + 255) / 256, 256, 0, stream>>>(pm, ps, Trow, nPad);
    fpacc_kernel<<<g2Blocks * 8, 512, 0, stream>>>(y, W2T, b2, Trow, partials, nAtoms, nPad);
    unsigned short* t = x; x = y; y = t;
  }
  reduce_kernel<<<(FPL + 255) / 256, 256, 0, stream>>>(partials, (float*)d_out, g2Blocks);
}